// Round 1
// baseline (10027.230 us; speedup 1.0000x reference)
//
#include <hip/hip_runtime.h>
#include <math.h>

#define EPSF 1e-5f

__device__ __forceinline__ float gelu_exact(float x) {
    return 0.5f * x * (1.0f + erff(x * 0.70710678118654752f));
}

// ---------------- embedding gather: h[row,:] = embed[x[row],:] ----------------
__global__ __launch_bounds__(128) void k_gather(const int* __restrict__ x,
                                                const float* __restrict__ embed,
                                                float* __restrict__ h) {
    int row = blockIdx.x;                 // 4096 rows
    int tok = x[row];
    const float4* src = (const float4*)(embed + (size_t)tok * 512);
    float4* dst = (float4*)(h + (size_t)row * 512);
    dst[threadIdx.x] = src[threadIdx.x];  // 128 threads * 4 floats = 512
}

// ------------- fused GEMM + bias + LayerNorm + exact GELU (N = 1024) -------------
// out[m,n] = gelu( LN_row(A@W + b + tscale*wx)[m,n] * g[n] + be[n] )
// Block: 256 threads, BM=8 rows, each thread owns 4 consecutive cols x 8 rows.
__global__ __launch_bounds__(256) void k_gemm_ln_gelu(
    const float* __restrict__ A, int K,
    const float* __restrict__ W,            // [K][1024] row-major
    const float* __restrict__ bvec,
    const float* __restrict__ wx, float tscale,
    const float* __restrict__ g, const float* __restrict__ be,
    float* __restrict__ out)
{
    const int BM = 8, BK = 64, N = 1024;
    __shared__ float As[BM][BK];
    __shared__ float red[4][BM][2];
    int t = threadIdx.x;
    int m0 = blockIdx.x * BM;
    int col = t * 4;

    float acc[BM][4];
    #pragma unroll
    for (int r = 0; r < BM; r++) { acc[r][0]=0.f; acc[r][1]=0.f; acc[r][2]=0.f; acc[r][3]=0.f; }

    int lr = t >> 5;            // 0..7 (A-tile row)
    int lk = (t & 31) * 2;      // 0..62 (A-tile k, 2 floats/thread)

    for (int kt = 0; kt < K; kt += BK) {
        float2 av = *(const float2*)&A[(size_t)(m0 + lr) * K + kt + lk];
        __syncthreads();
        As[lr][lk]     = av.x;
        As[lr][lk + 1] = av.y;
        __syncthreads();
        #pragma unroll 4
        for (int k = 0; k < BK; k++) {
            float4 w = *(const float4*)&W[(size_t)(kt + k) * N + col];
            #pragma unroll
            for (int r = 0; r < BM; r++) {
                float a = As[r][k];
                acc[r][0] = fmaf(a, w.x, acc[r][0]);
                acc[r][1] = fmaf(a, w.y, acc[r][1]);
                acc[r][2] = fmaf(a, w.z, acc[r][2]);
                acc[r][3] = fmaf(a, w.w, acc[r][3]);
            }
        }
    }

    // effective bias (folds the concat'd t_norm channel: beff = b + tscale*wx)
    float4 b4  = *(const float4*)&bvec[col];
    float4 wx4 = *(const float4*)&wx[col];
    float bb0 = b4.x + tscale * wx4.x;
    float bb1 = b4.y + tscale * wx4.y;
    float bb2 = b4.z + tscale * wx4.z;
    float bb3 = b4.w + tscale * wx4.w;

    float s1[BM], s2[BM];
    #pragma unroll
    for (int r = 0; r < BM; r++) {
        float z0 = acc[r][0] + bb0, z1 = acc[r][1] + bb1;
        float z2 = acc[r][2] + bb2, z3 = acc[r][3] + bb3;
        acc[r][0] = z0; acc[r][1] = z1; acc[r][2] = z2; acc[r][3] = z3;
        s1[r] = z0 + z1 + z2 + z3;
        s2[r] = z0*z0 + z1*z1 + z2*z2 + z3*z3;
    }

    // wave-level reduce (64 lanes)
    #pragma unroll
    for (int off = 32; off; off >>= 1) {
        #pragma unroll
        for (int r = 0; r < BM; r++) {
            s1[r] += __shfl_xor(s1[r], off);
            s2[r] += __shfl_xor(s2[r], off);
        }
    }
    int wid = t >> 6, lane = t & 63;
    if (lane == 0) {
        #pragma unroll
        for (int r = 0; r < BM; r++) { red[wid][r][0] = s1[r]; red[wid][r][1] = s2[r]; }
    }
    __syncthreads();

    float4 gv  = *(const float4*)&g[col];
    float4 bev = *(const float4*)&be[col];
    #pragma unroll
    for (int r = 0; r < BM; r++) {
        float t1 = red[0][r][0] + red[1][r][0] + red[2][r][0] + red[3][r][0];
        float t2 = red[0][r][1] + red[1][r][1] + red[2][r][1] + red[3][r][1];
        float mu   = t1 * (1.0f / 1024.0f);
        float var  = t2 * (1.0f / 1024.0f) - mu * mu;
        float rstd = rsqrtf(var + EPSF);
        float4 o;
        o.x = gelu_exact((acc[r][0] - mu) * rstd * gv.x + bev.x);
        o.y = gelu_exact((acc[r][1] - mu) * rstd * gv.y + bev.y);
        o.z = gelu_exact((acc[r][2] - mu) * rstd * gv.z + bev.z);
        o.w = gelu_exact((acc[r][3] - mu) * rstd * gv.w + bev.w);
        *(float4*)&out[(size_t)(m0 + r) * N + col] = o;
    }
}

// ---------- GEMM3 + diffusion update: h = (h - coef*(z2@W3 + b3)) * isa ----------
// A = z2 [M,1024], W3 [1024,512]. Block: 256 threads, BM=16 rows, 2 cols/thread.
__global__ __launch_bounds__(256) void k_gemm_update(
    const float* __restrict__ A,
    const float* __restrict__ W,
    const float* __restrict__ b,
    float* __restrict__ h,
    float coef, float isa)
{
    const int BM = 16, BK = 32, N = 512, K = 1024;
    __shared__ float As[BM][BK];
    int t = threadIdx.x;
    int m0 = blockIdx.x * BM;
    int col = t * 2;

    float acc[BM][2];
    #pragma unroll
    for (int r = 0; r < BM; r++) { acc[r][0] = 0.f; acc[r][1] = 0.f; }

    int lr = t >> 4;          // 0..15
    int lk = (t & 15) * 2;    // 0..30

    for (int kt = 0; kt < K; kt += BK) {
        float2 av = *(const float2*)&A[(size_t)(m0 + lr) * K + kt + lk];
        __syncthreads();
        *(float2*)&As[lr][lk] = av;
        __syncthreads();
        #pragma unroll 4
        for (int k = 0; k < BK; k++) {
            float2 w = *(const float2*)&W[(size_t)(kt + k) * N + col];
            #pragma unroll
            for (int r = 0; r < BM; r++) {
                float a = As[r][k];
                acc[r][0] = fmaf(a, w.x, acc[r][0]);
                acc[r][1] = fmaf(a, w.y, acc[r][1]);
            }
        }
    }

    float2 bv = *(const float2*)&b[col];
    #pragma unroll
    for (int r = 0; r < BM; r++) {
        size_t idx = (size_t)(m0 + r) * N + col;
        float2 hv = *(const float2*)&h[idx];
        float2 o;
        o.x = (hv.x - coef * (acc[r][0] + bv.x)) * isa;
        o.y = (hv.y - coef * (acc[r][1] + bv.y)) * isa;
        *(float2*)&h[idx] = o;
    }
}

// ---------------- final LayerNorm over width 512 ----------------
__global__ __launch_bounds__(128) void k_layernorm512(
    const float* __restrict__ h, const float* __restrict__ g,
    const float* __restrict__ b, float* __restrict__ out)
{
    int row = blockIdx.x;
    int t = threadIdx.x;
    float4 v = *(const float4*)&h[(size_t)row * 512 + t * 4];
    float s1 = v.x + v.y + v.z + v.w;
    float s2 = v.x*v.x + v.y*v.y + v.z*v.z + v.w*v.w;
    #pragma unroll
    for (int off = 32; off; off >>= 1) { s1 += __shfl_xor(s1, off); s2 += __shfl_xor(s2, off); }
    __shared__ float red[2][2];
    if ((t & 63) == 0) { red[t >> 6][0] = s1; red[t >> 6][1] = s2; }
    __syncthreads();
    float t1 = red[0][0] + red[1][0];
    float t2 = red[0][1] + red[1][1];
    float mu   = t1 * (1.0f / 512.0f);
    float var  = t2 * (1.0f / 512.0f) - mu * mu;
    float rstd = rsqrtf(var + EPSF);
    float4 gv = *(const float4*)&g[t * 4];
    float4 bv = *(const float4*)&b[t * 4];
    float4 o;
    o.x = (v.x - mu) * rstd * gv.x + bv.x;
    o.y = (v.y - mu) * rstd * gv.y + bv.y;
    o.z = (v.z - mu) * rstd * gv.z + bv.z;
    o.w = (v.w - mu) * rstd * gv.w + bv.w;
    *(float4*)&out[(size_t)row * 512 + t * 4] = o;
}

// ---------------- logits: C[m,v] = sum_k hc[m,k] * embed[v,k] ----------------
// 64x64x16 LDS-tiled f32 GEMM, B given transposed (embed rows are K-contiguous).
__global__ __launch_bounds__(256) void k_logits(
    const float* __restrict__ A,      // hc [4096, 512]
    const float* __restrict__ Bm,     // embed [32000, 512]
    float* __restrict__ C)            // [4096, 32000]
{
    const int BK = 16, K = 512, NN = 32000;
    __shared__ float As[BK][64 + 1];
    __shared__ float Bs[BK][64 + 1];
    int t  = threadIdx.x;
    int m0 = blockIdx.y * 64;
    int n0 = blockIdx.x * 64;
    int tx = t & 15, ty = t >> 4;

    float acc[4][4];
    #pragma unroll
    for (int i = 0; i < 4; i++)
        #pragma unroll
        for (int j = 0; j < 4; j++) acc[i][j] = 0.f;

    int lr = t >> 2;          // 0..63 (tile row)
    int lk = (t & 3) * 4;     // 0,4,8,12

    for (int kt = 0; kt < K; kt += BK) {
        float4 a4 = *(const float4*)&A [(size_t)(m0 + lr) * K + kt + lk];
        float4 b4 = *(const float4*)&Bm[(size_t)(n0 + lr) * K + kt + lk];
        __syncthreads();
        As[lk + 0][lr] = a4.x; As[lk + 1][lr] = a4.y; As[lk + 2][lr] = a4.z; As[lk + 3][lr] = a4.w;
        Bs[lk + 0][lr] = b4.x; Bs[lk + 1][lr] = b4.y; Bs[lk + 2][lr] = b4.z; Bs[lk + 3][lr] = b4.w;
        __syncthreads();
        #pragma unroll
        for (int k = 0; k < BK; k++) {
            float a0 = As[k][ty*4+0], a1 = As[k][ty*4+1], a2 = As[k][ty*4+2], a3 = As[k][ty*4+3];
            float b0 = Bs[k][tx*4+0], b1 = Bs[k][tx*4+1], b2 = Bs[k][tx*4+2], b3 = Bs[k][tx*4+3];
            acc[0][0] = fmaf(a0, b0, acc[0][0]); acc[0][1] = fmaf(a0, b1, acc[0][1]);
            acc[0][2] = fmaf(a0, b2, acc[0][2]); acc[0][3] = fmaf(a0, b3, acc[0][3]);
            acc[1][0] = fmaf(a1, b0, acc[1][0]); acc[1][1] = fmaf(a1, b1, acc[1][1]);
            acc[1][2] = fmaf(a1, b2, acc[1][2]); acc[1][3] = fmaf(a1, b3, acc[1][3]);
            acc[2][0] = fmaf(a2, b0, acc[2][0]); acc[2][1] = fmaf(a2, b1, acc[2][1]);
            acc[2][2] = fmaf(a2, b2, acc[2][2]); acc[2][3] = fmaf(a2, b3, acc[2][3]);
            acc[3][0] = fmaf(a3, b0, acc[3][0]); acc[3][1] = fmaf(a3, b1, acc[3][1]);
            acc[3][2] = fmaf(a3, b2, acc[3][2]); acc[3][3] = fmaf(a3, b3, acc[3][3]);
        }
    }

    #pragma unroll
    for (int i = 0; i < 4; i++) {
        float4 o = make_float4(acc[i][0], acc[i][1], acc[i][2], acc[i][3]);
        *(float4*)&C[(size_t)(m0 + ty * 4 + i) * NN + n0 + tx * 4] = o;
    }
}

extern "C" void kernel_launch(void* const* d_in, const int* in_sizes, int n_in,
                              void* d_out, int out_size, void* d_ws, size_t ws_size,
                              hipStream_t stream) {
    const int*   x     = (const int*)  d_in[0];
    const float* embed = (const float*)d_in[1];
    const float* W1    = (const float*)d_in[2];
    const float* b1    = (const float*)d_in[3];
    const float* g1    = (const float*)d_in[4];
    const float* be1   = (const float*)d_in[5];
    const float* W2    = (const float*)d_in[6];
    const float* b2    = (const float*)d_in[7];
    const float* g2    = (const float*)d_in[8];
    const float* be2   = (const float*)d_in[9];
    const float* W3    = (const float*)d_in[10];
    const float* b3    = (const float*)d_in[11];
    const float* gn    = (const float*)d_in[12];
    const float* bn    = (const float*)d_in[13];
    float* out = (float*)d_out;

    char* ws = (char*)d_ws;
    float* h  = (float*)(ws);                          //  8 MB  [4096,512]
    float* z1 = (float*)(ws + ((size_t)8  << 20));     // 16 MB  [4096,1024]
    float* z2 = (float*)(ws + ((size_t)24 << 20));     // 16 MB  [4096,1024]
    float* hc = (float*)(ws + ((size_t)40 << 20));     //  8 MB  [4096,512]

    const int M = 4096;

    k_gather<<<M, 128, 0, stream>>>(x, embed, h);

    // host-side per-step scalars (deterministic; computed identically every call)
    double betas[20], acp[20];
    double run = 1.0;
    for (int i = 0; i < 20; i++) {
        betas[i] = 1e-4 + (0.02 - 1e-4) * (double)i / 19.0;
        run *= (1.0 - betas[i]);
        acp[i] = run;
    }
    for (int j = 0; j < 20; j++) {
        int tt = 19 - j;
        float tn   = (float)tt / 20.0f;
        float coef = (float)(betas[tt] / sqrt(1.0 - acp[tt]));
        float isa  = (float)(1.0 / sqrt(1.0 - betas[tt]));

        k_gemm_ln_gelu<<<M / 8, 256, 0, stream>>>(h, 512, W1, b1, W1 + (size_t)512 * 1024, tn,
                                                  g1, be1, z1);
        k_gemm_ln_gelu<<<M / 8, 256, 0, stream>>>(z1, 1024, W2, b2, b2, 0.0f,
                                                  g2, be2, z2);
        k_gemm_update<<<M / 16, 256, 0, stream>>>(z2, W3, b3, h, coef, isa);
    }

    k_layernorm512<<<M, 128, 0, stream>>>(h, gn, bn, hc);

    dim3 lgrid(32000 / 64, M / 64);
    k_logits<<<lgrid, 256, 0, stream>>>(hc, embed, out);
}

// Round 2
// 2478.217 us; speedup vs baseline: 4.0461x; 4.0461x over previous
//
#include <hip/hip_runtime.h>
#include <math.h>

typedef unsigned int u32;
typedef unsigned short u16;
typedef __attribute__((ext_vector_type(4))) float f32x4;
typedef __attribute__((ext_vector_type(8))) short bf16x8;

#define EPSF 1e-5f

__device__ __forceinline__ u16 f2bf(float f) {
    u32 u = __builtin_bit_cast(u32, f);
    u += 0x7fff + ((u >> 16) & 1);          // round-to-nearest-even
    return (u16)(u >> 16);
}

__device__ __forceinline__ float gelu_exact(float x) {
    return 0.5f * x * (1.0f + erff(x * 0.70710678118654752f));
}

typedef const __attribute__((address_space(1))) void* gas_t;
typedef __attribute__((address_space(3))) void* las_t;
#define GLOAD_LDS16(g, l) __builtin_amdgcn_global_load_lds((gas_t)(g), (las_t)(l), 16, 0, 0)

// ---------------- f32 -> bf16 elementwise convert (embed) ----------------
__global__ __launch_bounds__(256) void k_f2bf_vec(const float* __restrict__ in,
                                                  u16* __restrict__ out, int n4) {
    int i = blockIdx.x * 256 + threadIdx.x;
    if (i < n4) {
        float4 v = ((const float4*)in)[i];
        ushort4 o;
        o.x = f2bf(v.x); o.y = f2bf(v.y); o.z = f2bf(v.z); o.w = f2bf(v.w);
        ((ushort4*)out)[i] = o;
    }
}

// ---------------- transpose + convert: in f32 [R][C] -> out bf16 [C][R] ----------------
__global__ __launch_bounds__(256) void k_transpose_bf(const float* __restrict__ in,
                                                      u16* __restrict__ out, int R, int C) {
    __shared__ float tile[32][33];
    int c0 = blockIdx.x * 32, r0 = blockIdx.y * 32;
    int tx = threadIdx.x & 31, ty = threadIdx.x >> 5;   // ty 0..7
    #pragma unroll
    for (int i = 0; i < 32; i += 8)
        tile[ty + i][tx] = in[(size_t)(r0 + ty + i) * C + c0 + tx];
    __syncthreads();
    #pragma unroll
    for (int i = 0; i < 32; i += 8)
        out[(size_t)(c0 + ty + i) * R + r0 + tx] = f2bf(tile[tx][ty + i]);
}

// ---------------- embedding gather: h f32 + hb bf16 ----------------
__global__ __launch_bounds__(128) void k_gather(const int* __restrict__ x,
                                                const float* __restrict__ embed,
                                                float* __restrict__ h, u16* __restrict__ hb) {
    int row = blockIdx.x;
    int tok = x[row];
    int t = threadIdx.x;
    float4 v = *(const float4*)(embed + (size_t)tok * 512 + t * 4);
    *(float4*)(h + (size_t)row * 512 + t * 4) = v;
    ushort4 o;
    o.x = f2bf(v.x); o.y = f2bf(v.y); o.z = f2bf(v.z); o.w = f2bf(v.w);
    *(ushort4*)(hb + (size_t)row * 512 + t * 4) = o;
}

// ---------------- MFMA bf16 GEMM, 128x128 tile, BK=64, 4 waves ----------------
// A [M][K] bf16, BT [N][K] bf16 (B transposed). C row-major, ldc.
// EPI 0: C = acc                       (logits)
// EPI 1: C = acc + bias + tscale*wx    (pre-LN z, f32)
// EPI 2: h = (h - coef*(acc+bias))*isa ; also write bf16 mirror Cb
template<int EPI>
__global__ __launch_bounds__(256) void k_gemm(
    const u16* __restrict__ A, const u16* __restrict__ BT,
    int K, int ldc,
    float* __restrict__ C, u16* __restrict__ Cb,
    const float* __restrict__ bias, const float* __restrict__ wx,
    float tscale, float coef, float isa)
{
    __shared__ __align__(16) u16 As[128 * 64];
    __shared__ __align__(16) u16 Bs[128 * 64];
    int t = threadIdx.x;
    int w = t >> 6, lane = t & 63;
    int m0 = blockIdx.y * 128;
    int n0 = blockIdx.x * 128;
    int wr = (w >> 1) * 64, wc = (w & 1) * 64;

    f32x4 acc[4][4];
    #pragma unroll
    for (int mi = 0; mi < 4; mi++)
        #pragma unroll
        for (int ni = 0; ni < 4; ni++)
            acc[mi][ni] = (f32x4){0.f, 0.f, 0.f, 0.f};

    int srow = lane >> 3;            // 0..7
    int scol = (lane & 7) * 8;       // element offset along K, 16B chunks

    const u16* Ab = A + (size_t)m0 * K;
    const u16* Bb = BT + (size_t)n0 * K;

    const int mrow = wr + (lane & 15);
    const int ncol = wc + (lane & 15);
    const int ksl = (lane >> 4) * 8;

    for (int kt = 0; kt < K; kt += 64) {
        __syncthreads();   // previous tile fully consumed before overwrite
        #pragma unroll
        for (int i = 0; i < 4; i++) {
            int c = i * 4 + w;                // LDS chunk id 0..15 (1KB each)
            int row = c * 8 + srow;           // tile row 0..127
            GLOAD_LDS16(Ab + (size_t)row * K + kt + scol, &As[c * 512]);
            GLOAD_LDS16(Bb + (size_t)row * K + kt + scol, &Bs[c * 512]);
        }
        __syncthreads();   // compiler drains vmcnt(0) here

        #pragma unroll
        for (int kk = 0; kk < 64; kk += 32) {
            bf16x8 a[4], b[4];
            #pragma unroll
            for (int mi = 0; mi < 4; mi++)
                a[mi] = *(const bf16x8*)&As[(mrow + mi * 16) * 64 + kk + ksl];
            #pragma unroll
            for (int ni = 0; ni < 4; ni++)
                b[ni] = *(const bf16x8*)&Bs[(ncol + ni * 16) * 64 + kk + ksl];
            #pragma unroll
            for (int mi = 0; mi < 4; mi++)
                #pragma unroll
                for (int ni = 0; ni < 4; ni++)
                    acc[mi][ni] = __builtin_amdgcn_mfma_f32_16x16x32_bf16(
                        a[mi], b[ni], acc[mi][ni], 0, 0, 0);
        }
    }

    float bb[4];
    if constexpr (EPI != 0) {
        #pragma unroll
        for (int ni = 0; ni < 4; ni++) {
            int col = n0 + wc + ni * 16 + (lane & 15);
            bb[ni] = bias[col] + tscale * wx[col];
        }
    }

    #pragma unroll
    for (int mi = 0; mi < 4; mi++) {
        #pragma unroll
        for (int j = 0; j < 4; j++) {
            int row = m0 + wr + mi * 16 + ((lane >> 4) << 2) + j;
            #pragma unroll
            for (int ni = 0; ni < 4; ni++) {
                int col = n0 + wc + ni * 16 + (lane & 15);
                size_t idx = (size_t)row * ldc + col;
                float v = acc[mi][ni][j];
                if constexpr (EPI == 0) {
                    C[idx] = v;
                } else if constexpr (EPI == 1) {
                    C[idx] = v + bb[ni];
                } else {
                    float nh = (C[idx] - coef * (v + bb[ni])) * isa;
                    C[idx] = nh;
                    Cb[idx] = f2bf(nh);
                }
            }
        }
    }
}

// ---------------- LayerNorm + exact GELU over width 1024, bf16 out ----------------
__global__ __launch_bounds__(256) void k_ln_gelu(const float* __restrict__ z,
                                                 const float* __restrict__ g,
                                                 const float* __restrict__ be,
                                                 u16* __restrict__ out) {
    int row = blockIdx.x, t = threadIdx.x;
    float4 v = *(const float4*)&z[(size_t)row * 1024 + t * 4];
    float s1 = v.x + v.y + v.z + v.w;
    float s2 = v.x * v.x + v.y * v.y + v.z * v.z + v.w * v.w;
    #pragma unroll
    for (int off = 32; off; off >>= 1) { s1 += __shfl_xor(s1, off); s2 += __shfl_xor(s2, off); }
    __shared__ float red[4][2];
    int wid = t >> 6;
    if ((t & 63) == 0) { red[wid][0] = s1; red[wid][1] = s2; }
    __syncthreads();
    float t1 = red[0][0] + red[1][0] + red[2][0] + red[3][0];
    float t2 = red[0][1] + red[1][1] + red[2][1] + red[3][1];
    float mu = t1 * (1.0f / 1024.0f);
    float var = t2 * (1.0f / 1024.0f) - mu * mu;
    float rstd = rsqrtf(var + EPSF);
    float4 gv = *(const float4*)&g[t * 4];
    float4 bev = *(const float4*)&be[t * 4];
    ushort4 o;
    o.x = f2bf(gelu_exact((v.x - mu) * rstd * gv.x + bev.x));
    o.y = f2bf(gelu_exact((v.y - mu) * rstd * gv.y + bev.y));
    o.z = f2bf(gelu_exact((v.z - mu) * rstd * gv.z + bev.z));
    o.w = f2bf(gelu_exact((v.w - mu) * rstd * gv.w + bev.w));
    *(ushort4*)&out[(size_t)row * 1024 + t * 4] = o;
}

// ---------------- final LayerNorm over width 512, bf16 out ----------------
__global__ __launch_bounds__(128) void k_ln512(const float* __restrict__ h,
                                               const float* __restrict__ g,
                                               const float* __restrict__ b,
                                               u16* __restrict__ out) {
    int row = blockIdx.x, t = threadIdx.x;
    float4 v = *(const float4*)&h[(size_t)row * 512 + t * 4];
    float s1 = v.x + v.y + v.z + v.w;
    float s2 = v.x * v.x + v.y * v.y + v.z * v.z + v.w * v.w;
    #pragma unroll
    for (int off = 32; off; off >>= 1) { s1 += __shfl_xor(s1, off); s2 += __shfl_xor(s2, off); }
    __shared__ float red[2][2];
    if ((t & 63) == 0) { red[t >> 6][0] = s1; red[t >> 6][1] = s2; }
    __syncthreads();
    float t1 = red[0][0] + red[1][0];
    float t2 = red[0][1] + red[1][1];
    float mu = t1 * (1.0f / 512.0f);
    float var = t2 * (1.0f / 512.0f) - mu * mu;
    float rstd = rsqrtf(var + EPSF);
    float4 gv = *(const float4*)&g[t * 4];
    float4 bv = *(const float4*)&b[t * 4];
    ushort4 o;
    o.x = f2bf((v.x - mu) * rstd * gv.x + bv.x);
    o.y = f2bf((v.y - mu) * rstd * gv.y + bv.y);
    o.z = f2bf((v.z - mu) * rstd * gv.z + bv.z);
    o.w = f2bf((v.w - mu) * rstd * gv.w + bv.w);
    *(ushort4*)&out[(size_t)row * 512 + t * 4] = o;
}

extern "C" void kernel_launch(void* const* d_in, const int* in_sizes, int n_in,
                              void* d_out, int out_size, void* d_ws, size_t ws_size,
                              hipStream_t stream) {
    const int*   x     = (const int*)  d_in[0];
    const float* embed = (const float*)d_in[1];
    const float* W1    = (const float*)d_in[2];
    const float* b1    = (const float*)d_in[3];
    const float* g1    = (const float*)d_in[4];
    const float* be1   = (const float*)d_in[5];
    const float* W2    = (const float*)d_in[6];
    const float* b2    = (const float*)d_in[7];
    const float* g2    = (const float*)d_in[8];
    const float* be2   = (const float*)d_in[9];
    const float* W3    = (const float*)d_in[10];
    const float* b3    = (const float*)d_in[11];
    const float* gn    = (const float*)d_in[12];
    const float* bn    = (const float*)d_in[13];
    float* out = (float*)d_out;

    char* ws = (char*)d_ws;
    float* h    = (float*)(ws);                      //  8 MiB [4096,512] f32
    u16*   hb   = (u16*)  (ws + (8ull  << 20));      //  4 MiB [4096,512] bf16
    float* zf   = (float*)(ws + (12ull << 20));      // 16 MiB [4096,1024] f32 (z1/z2 reuse)
    u16*   z1b  = (u16*)  (ws + (28ull << 20));      //  8 MiB [4096,1024] bf16
    u16*   z2b  = (u16*)  (ws + (36ull << 20));      //  8 MiB [4096,1024] bf16
    u16*   embB = (u16*)  (ws + (44ull << 20));      // 31.25 MiB [32000,512] bf16
    u16*   W1T  = (u16*)  (ws + (76ull << 20));      //  1 MiB [1024,512]
    u16*   W2T  = (u16*)  (ws + (77ull << 20));      //  2 MiB [1024,1024]
    u16*   W3T  = (u16*)  (ws + (79ull << 20));      //  1 MiB [512,1024]
    u16*   hcb  = z1b;                               // reuse (dead by final LN)

    const int M = 4096;

    // once-per-call weight conversions
    k_f2bf_vec<<<16000, 256, 0, stream>>>(embed, embB, 32000 * 512 / 4);
    k_transpose_bf<<<dim3(32, 16), 256, 0, stream>>>(W1, W1T, 512, 1024);
    k_transpose_bf<<<dim3(32, 32), 256, 0, stream>>>(W2, W2T, 1024, 1024);
    k_transpose_bf<<<dim3(16, 32), 256, 0, stream>>>(W3, W3T, 1024, 512);
    k_gather<<<M, 128, 0, stream>>>(x, embed, h, hb);

    double betas[20], acp[20];
    double run = 1.0;
    for (int i = 0; i < 20; i++) {
        betas[i] = 1e-4 + (0.02 - 1e-4) * (double)i / 19.0;
        run *= (1.0 - betas[i]);
        acp[i] = run;
    }
    const float* wxrow = W1 + (size_t)512 * 1024;   // concat'd t channel weights

    for (int j = 0; j < 20; j++) {
        int tt = 19 - j;
        float tn   = (float)tt / 20.0f;
        float coef = (float)(betas[tt] / sqrt(1.0 - acp[tt]));
        float isa  = (float)(1.0 / sqrt(1.0 - betas[tt]));

        k_gemm<1><<<dim3(8, 32), 256, 0, stream>>>(hb, W1T, 512, 1024, zf, nullptr,
                                                   b1, wxrow, tn, 0.f, 0.f);
        k_ln_gelu<<<M, 256, 0, stream>>>(zf, g1, be1, z1b);
        k_gemm<1><<<dim3(8, 32), 256, 0, stream>>>(z1b, W2T, 1024, 1024, zf, nullptr,
                                                   b2, b2, 0.f, 0.f, 0.f);
        k_ln_gelu<<<M, 256, 0, stream>>>(zf, g2, be2, z2b);
        k_gemm<2><<<dim3(4, 32), 256, 0, stream>>>(z2b, W3T, 1024, 512, h, hb,
                                                   b3, b3, 0.f, coef, isa);
    }

    k_ln512<<<M, 128, 0, stream>>>(h, gn, bn, hcb);
    k_gemm<0><<<dim3(250, 32), 256, 0, stream>>>(hcb, embB, 512, 32000, out, nullptr,
                                                 nullptr, nullptr, 0.f, 0.f, 0.f);
}